// Round 7
// baseline (2000.573 us; speedup 1.0000x reference)
//
#include <hip/hip_runtime.h>
#include <math.h>

#define Hh 100
#define Ww 150
#define Mm 15000
#define NP 135000   // 15000*9

typedef double f64x4 __attribute__((ext_vector_type(4)));

// f64 MFMA: builtin exists only in the device pass; host pass parses but never runs it.
#if defined(__HIP_DEVICE_COMPILE__)
#if __has_builtin(__builtin_amdgcn_mfma_f64_16x16x4f64)
#define MFMA64(a,b,c) __builtin_amdgcn_mfma_f64_16x16x4f64((a),(b),(c),0,0,0)
#elif __has_builtin(__builtin_amdgcn_mfma_f64_16x16x4_f64)
#define MFMA64(a,b,c) __builtin_amdgcn_mfma_f64_16x16x4_f64((a),(b),(c),0,0,0)
#else
#error "no f64 mfma builtin on device"
#endif
#else
#define MFMA64(a,b,c) (c)
#endif

__constant__ double ANCH[9][4] = {
  {-84.0,-40.0,99.0,55.0},{-176.0,-88.0,191.0,103.0},{-360.0,-184.0,375.0,191.0},
  {-56.0,-56.0,71.0,71.0},{-120.0,-120.0,135.0,135.0},{-248.0,-248.0,263.0,263.0},
  {-36.0,-80.0,51.0,95.0},{-80.0,-168.0,95.0,183.0},{-168.0,-344.0,183.0,359.0}};

// ---------------- prep: LDS-tiled transpose of conv1 weights to [tap][ci][co] ----------------
__global__ __launch_bounds__(256) void prep_wT(const float* __restrict__ w,
                                               float* __restrict__ wT) {
  __shared__ float t[32][32][10];  // [ci][co][tap], pad 9->10
  const int co0 = blockIdx.x * 32, ci0 = blockIdx.y * 32;
  for (int e = threadIdx.x; e < 9216; e += 256) {
    int cr = e / 288;
    int rem = e - cr * 288;
    int cir = rem / 9, tap = rem - cir * 9;
    t[cir][cr][tap] = w[(size_t)(co0 + cr) * 4608 + (ci0 + cir) * 9 + tap];
  }
  __syncthreads();
  for (int e = threadIdx.x; e < 9216; e += 256) {
    int tap = e / 1024;
    int rem = e - tap * 1024;
    int cir = rem >> 5, cr = rem & 31;
    wT[(size_t)tap * 262144 + (size_t)(ci0 + cir) * 512 + (co0 + cr)] = t[cir][cr][tap];
  }
}

// ---------------- prep: f64 1x1 weights ----------------
__global__ void prep_w54(const float* __restrict__ sw, const float* __restrict__ bw,
                         double* __restrict__ w54) {
  int idx = blockIdx.x * 256 + threadIdx.x;
  if (idx < 54 * 512) {
    int o = idx >> 9, c = idx & 511;
    w54[idx] = (double)((o < 18) ? sw[o * 512 + c] : bw[(o - 18) * 512 + c]);
  }
}

// ---------------- conv3x3 512->512 SAME + bias + relu via f64 MFMA, 2-phase pipeline ----------------
// block: 256 thr = 4 waves; tile 64px x 128co; wave tile 32px x 64co (2 M-frag x 4 N-frag).
// Double-buffered LDS + register prefetch: one barrier per 32-K chunk, global latency
// hidden under MFMA. D layout derived at runtime by probe MFMAs.
__global__ __launch_bounds__(256, 3) void conv3x3(const float* __restrict__ feat,
                                                  const float* __restrict__ wT,
                                                  const float* __restrict__ bias,
                                                  float* __restrict__ x) {
  __shared__ union {
    struct { float A[2][32][72]; float B[2][32][136]; } s;  // 53.2 KB dbuf
    float Lx[128][65];                                       // 33.3 KB epilogue transpose
  } sm;
  const int tid = threadIdx.x;
  const int lane = tid & 63;
  const int wv = tid >> 6;            // wave 0..3
  const int pw = (wv & 1) * 32;       // wave px offset
  const int cw = (wv >> 1) * 64;      // wave co offset
  const int m0 = blockIdx.x * 64;
  const int n0 = blockIdx.y * 128;
  const int l15 = lane & 15, l4 = lane >> 4;

  // --- derive D fragment layout ---
  f64x4 zero; zero[0] = 0.0; zero[1] = 0.0; zero[2] = 0.0; zero[3] = 0.0;
  const double ap1 = (l4 == 0) ? (double)l15 : 0.0;
  const double bp1 = (l4 == 0) ? 1.0 : 0.0;
  const f64x4 rowp = MFMA64(ap1, bp1, zero);          // D[i][j] = i
  const double ap2 = (l4 == 0) ? 1.0 : 0.0;
  const double bp2 = (l4 == 0) ? (double)l15 : 0.0;
  const f64x4 colp = MFMA64(ap2, bp2, zero);          // D[i][j] = j
  int rowm[4], colm[4];
#pragma unroll
  for (int r = 0; r < 4; ++r) { rowm[r] = (int)rowp[r]; colm[r] = (int)colp[r]; }

  f64x4 acc[2][4];
#pragma unroll
  for (int i = 0; i < 2; ++i)
#pragma unroll
    for (int q = 0; q < 4; ++q) acc[i][q] = zero;

  // A staging: thread -> (px = tid&63, k = (tid>>6)*8 + kk)
  const int pa = tid & 63;
  const int ka = (tid >> 6) * 8;
  const int ma = m0 + pa;
  const int ha = ma / 150, wa = ma - ha * 150;
  // B staging: thread -> (co-quad = tid&31, k = (tid>>5)*4 + kk)
  const int cq = tid & 31;
  const int kb = (tid >> 5) * 4;

  float aR[8];
  float4 bR[4];

  // chunk c (0..143): tap = c>>4, cb = (c&15)*32
  auto loadRegs = [&](int c) {
    const int tap = c >> 4;
    const int cb = (c & 15) << 5;
    const int dy = tap / 3 - 1, dx = tap - (tap / 3) * 3 - 1;
    const int hh = ha + dy, wwp = wa + dx;
    const bool ok = (ma < Mm) && (hh >= 0) && (hh < Hh) && (wwp >= 0) && (wwp < Ww);
    const int src = hh * Ww + wwp;
#pragma unroll
    for (int kk = 0; kk < 8; ++kk)
      aR[kk] = ok ? feat[(size_t)(cb + ka + kk) * Mm + src] : 0.0f;
    const float* wb = wT + (size_t)tap * 262144 + n0;
#pragma unroll
    for (int kk = 0; kk < 4; ++kk)
      bR[kk] = *(const float4*)&wb[(size_t)(cb + kb + kk) * 512 + cq * 4];
  };
  auto writeLDS = [&](int b) {
#pragma unroll
    for (int kk = 0; kk < 8; ++kk) sm.s.A[b][ka + kk][pa] = aR[kk];
#pragma unroll
    for (int kk = 0; kk < 4; ++kk) *(float4*)&sm.s.B[b][kb + kk][cq * 4] = bR[kk];
  };

  loadRegs(0);
  writeLDS(0);
  loadRegs(1);
  __syncthreads();

  for (int c = 0; c < 144; ++c) {
    const int b = c & 1;
#pragma unroll
    for (int t = 0; t < 8; ++t) {
      const int kt = t * 4 + l4;
      const double a0 = (double)sm.s.A[b][kt][pw + l15];
      const double a1 = (double)sm.s.A[b][kt][pw + 16 + l15];
      const double b0 = (double)sm.s.B[b][kt][cw + l15];
      const double b1 = (double)sm.s.B[b][kt][cw + 16 + l15];
      const double b2 = (double)sm.s.B[b][kt][cw + 32 + l15];
      const double b3 = (double)sm.s.B[b][kt][cw + 48 + l15];
      acc[0][0] = MFMA64(a0, b0, acc[0][0]);
      acc[0][1] = MFMA64(a0, b1, acc[0][1]);
      acc[0][2] = MFMA64(a0, b2, acc[0][2]);
      acc[0][3] = MFMA64(a0, b3, acc[0][3]);
      acc[1][0] = MFMA64(a1, b0, acc[1][0]);
      acc[1][1] = MFMA64(a1, b1, acc[1][1]);
      acc[1][2] = MFMA64(a1, b2, acc[1][2]);
      acc[1][3] = MFMA64(a1, b3, acc[1][3]);
    }
    if (c + 1 < 144) {
      writeLDS(b ^ 1);                 // stage chunk c+1 (regs loaded a chunk ago)
      if (c + 2 < 144) loadRegs(c + 2);
      __syncthreads();
    }
  }
  __syncthreads();
  // epilogue: bias + relu in f64, layout-probe-driven transpose via LDS, coalesced store
#pragma unroll
  for (int i = 0; i < 2; ++i)
#pragma unroll
    for (int q = 0; q < 4; ++q)
#pragma unroll
      for (int r = 0; r < 4; ++r) {
        const int row = pw + i * 16 + rowm[r];        // pixel within tile
        const int col = cw + q * 16 + colm[r];        // out-channel within tile
        const double v = acc[i][q][r] + (double)bias[n0 + col];
        sm.Lx[col][row] = (float)(v > 0.0 ? v : 0.0);
      }
  __syncthreads();
  for (int e = tid; e < 64 * 128; e += 256) {
    const int co = e >> 6, p = e & 63;
    const int m = m0 + p;
    if (m < Mm) x[(size_t)(n0 + co) * Mm + m] = sm.Lx[co][p];
  }
}

// ---------------- fused 1x1 convs: 18 cls + 36 deltas, f64 accumulate, split over 6 groups ----------------
__global__ __launch_bounds__(256) void conv1x1(const float* __restrict__ x,
                                               const double* __restrict__ w54,
                                               const float* __restrict__ sb,
                                               const float* __restrict__ bb,
                                               float* __restrict__ cls,
                                               float* __restrict__ dl) {
  int m = blockIdx.x * 256 + threadIdx.x;
  int g = blockIdx.y;  // 0..5, each handles 9 outputs
  double acc[9];
#pragma unroll
  for (int o = 0; o < 9; ++o) acc[o] = 0.0;
  if (m < Mm) {
    const double* wg = w54 + (size_t)g * 9 * 512;
    for (int c = 0; c < 512; ++c) {
      double v = (double)x[(size_t)c * Mm + m];
#pragma unroll
      for (int o = 0; o < 9; ++o) acc[o] += v * wg[o * 512 + c];
    }
#pragma unroll
    for (int o = 0; o < 9; ++o) {
      int oo = g * 9 + o;
      if (oo < 18) cls[oo * Mm + m] = (float)(acc[o] + (double)sb[oo]);
      else dl[(oo - 18) * Mm + m] = (float)(acc[o] + (double)bb[oo - 18]);
    }
  }
}

// ---------------- softmax + box decode + filter + sortable keys (+ fused histogram) ----------------
__global__ void decode(const float* __restrict__ cls, const float* __restrict__ dl,
                       const float* __restrict__ info, double4* __restrict__ props,
                       float* __restrict__ scoresF, unsigned long long* __restrict__ keys64,
                       unsigned* __restrict__ keys32, unsigned* __restrict__ hist) {
  int i = blockIdx.x * 256 + threadIdx.x;
  if (i >= NP) return;
  int m = i / 9, a = i - m * 9;
  int h = m / 150, w = m - h * 150;
  double c0 = (double)cls[a * Mm + m], c1 = (double)cls[(9 + a) * Mm + m];
  double mx = fmax(c0, c1);
  double e0 = exp(c0 - mx), e1 = exp(c1 - mx);
  double p = e1 / (e0 + e1);
  double d0 = (double)dl[(a * 4 + 0) * Mm + m], d1 = (double)dl[(a * 4 + 1) * Mm + m];
  double d2 = (double)dl[(a * 4 + 2) * Mm + m], d3 = (double)dl[(a * 4 + 3) * Mm + m];
  double sx = (double)w * 16.0, sy = (double)h * 16.0;
  double ax1 = ANCH[a][0] + sx, ay1 = ANCH[a][1] + sy;
  double ax2 = ANCH[a][2] + sx, ay2 = ANCH[a][3] + sy;
  double aw = ax2 - ax1 + 1.0, ah = ay2 - ay1 + 1.0;
  double cx = ax1 + 0.5 * aw, cy = ay1 + 0.5 * ah;
  double pcx = d0 * aw + cx, pcy = d1 * ah + cy;
  double pw = exp(d2) * aw, ph = exp(d3) * ah;
  double x1 = pcx - 0.5 * pw, y1 = pcy - 0.5 * ph;
  double x2 = pcx + 0.5 * pw, y2 = pcy + 0.5 * ph;
  double IH = (double)info[0], IW = (double)info[1], sc = (double)info[2];
  x1 = fmin(fmax(x1, 0.0), IW - 1.0); y1 = fmin(fmax(y1, 0.0), IH - 1.0);
  x2 = fmin(fmax(x2, 0.0), IW - 1.0); y2 = fmin(fmax(y2, 0.0), IH - 1.0);
  double bwd = x2 - x1 + 1.0, bhd = y2 - y1 + 1.0;
  bool valid = (bwd >= 16.0 * sc) && (bhd >= 16.0 * sc);
  double score = valid ? p : -__builtin_inf();
  double4 pr; pr.x = x1; pr.y = y1; pr.z = x2; pr.w = y2;
  props[i] = pr;
  float pf = (float)score;
  scoresF[i] = pf;
  unsigned long long b = (unsigned long long)__double_as_longlong(score);
  unsigned long long s = (b >> 63) ? ~b : (b | 0x8000000000000000ull);
  unsigned long long k = ~s;                      // ascending key == descending score
  keys64[i] = (k & ~0x3FFFFull) | (unsigned long long)i;  // idx tiebreak (stable top_k)
  unsigned ub = __float_as_uint(pf);
  unsigned us = (ub >> 31) ? ~ub : (ub | 0x80000000u);
  unsigned k32 = ~us;
  keys32[i] = k32;
  atomicAdd(&hist[k32 >> 16], 1u);
}

// ---------------- find cutoff bin B: cum(<=B) >= 2000, cum(<B) < 2000 ----------------
__global__ __launch_bounds__(1024) void cutoff_k(const unsigned* __restrict__ hist,
                                                 int* __restrict__ Bout) {
  __shared__ unsigned ps[1024];
  int t = threadIdx.x;
  unsigned s = 0;
  for (int b = t * 64; b < t * 64 + 64; ++b) s += hist[b];
  ps[t] = s; __syncthreads();
  for (int off = 1; off < 1024; off <<= 1) {
    unsigned a = ps[t];
    unsigned bb2 = (t >= off) ? ps[t - off] : 0u;
    __syncthreads();
    ps[t] = a + bb2;
    __syncthreads();
  }
  unsigned excl = ps[t] - s;
  if (excl < 2000u) {
    unsigned run = excl;
    for (int b = t * 64; b < t * 64 + 64; ++b) {
      unsigned nb = run + hist[b];
      if (run < 2000u && nb >= 2000u) *Bout = b;
      run = nb;
    }
  }
}

// ---------------- compact candidates (bin <= B) ----------------
__global__ void compact_k(const unsigned* __restrict__ keys32,
                          const unsigned long long* __restrict__ keys64,
                          const int* __restrict__ Bptr,
                          unsigned long long* __restrict__ cand, int* __restrict__ cnt) {
  int i = blockIdx.x * 256 + threadIdx.x;
  if (i >= NP) return;
  int B = *Bptr;
  if ((int)(keys32[i] >> 16) <= B) {
    int pos = atomicAdd(cnt, 1);
    if (pos < 8192) cand[pos] = keys64[i];
  }
}

// ---------------- single-block bitonic sort of 8192 candidate keys; emit top-2000 ----------------
__global__ __launch_bounds__(1024) void sort_top(const unsigned long long* __restrict__ cand,
                                                 const int* __restrict__ pcnt,
                                                 const double4* __restrict__ props,
                                                 const float* __restrict__ scoresF,
                                                 double4* __restrict__ boxes2000,
                                                 float* __restrict__ score2000) {
  __shared__ unsigned long long sh[8192];  // 64 KB
  int t = threadIdx.x;
  int cnt = *pcnt; if (cnt > 8192) cnt = 8192;
  for (int i = t; i < 8192; i += 1024) sh[i] = (i < cnt) ? cand[i] : ~0ull;
  __syncthreads();
  for (int kb = 1; kb <= 13; ++kb) {
    int k = 1 << kb;
    for (int jb = kb - 1; jb >= 0; --jb) {
      int j = 1 << jb;
      for (int s = t; s < 4096; s += 1024) {
        int i = ((s >> jb) << (jb + 1)) | (s & (j - 1));
        int l = i + j;
        bool up = ((i & k) == 0);
        unsigned long long a = sh[i], b = sh[l];
        if (up ? (a > b) : (a < b)) { sh[i] = b; sh[l] = a; }
      }
      __syncthreads();
    }
  }
  for (int r = t; r < 2000; r += 1024) {
    unsigned long long key = sh[r];
    int idx = (int)(key & 0x3FFFFull);
    boxes2000[r] = props[idx];
    score2000[r] = scoresF[idx];
  }
}

// ---------------- NMS pairwise IoU bitmask (f64) ----------------
__global__ __launch_bounds__(256) void nms_mask(const double4* __restrict__ boxes,
                                                unsigned long long* __restrict__ mask) {
  int tid = threadIdx.x;
  int r = blockIdx.x * 8 + (tid >> 5);
  int wd = tid & 31;
  double4 bi = boxes[r];
  double ai = (bi.z - bi.x + 1.0) * (bi.w - bi.y + 1.0);
  unsigned long long bits = 0;
  int j0 = wd * 64;
  int jmax = 2000 - j0; if (jmax > 64) jmax = 64;
  for (int jj = 0; jj < jmax; ++jj) {
    int j = j0 + jj;
    if (j > r) {
      double4 bj = boxes[j];
      double xx1 = fmax(bi.x, bj.x), yy1 = fmax(bi.y, bj.y);
      double xx2 = fmin(bi.z, bj.z), yy2 = fmin(bi.w, bj.w);
      double w_ = fmax(xx2 - xx1 + 1.0, 0.0), h_ = fmax(yy2 - yy1 + 1.0, 0.0);
      double inter = w_ * h_;
      double aj = (bj.z - bj.x + 1.0) * (bj.w - bj.y + 1.0);
      double iou = inter / (ai + aj - inter);
      if (iou > 0.7) bits |= 1ull << jj;
    }
  }
  mask[r * 32 + wd] = bits;
}

// ---------------- sequential greedy suppress (single wave, shfl alive-bitmask) ----------------
__global__ __launch_bounds__(256) void suppress(const unsigned long long* __restrict__ mask,
                                                unsigned long long* __restrict__ aliveOut) {
  __shared__ unsigned long long rows[64][32];  // 16 KB chunk of mask rows
  int tid = threadIdx.x;
  int lane = tid & 63;
  unsigned long long myword = 0;
  if (tid < 64) {
    if (lane < 31) myword = ~0ull;
    else if (lane == 31) myword = 0xFFFFull;  // bits 1984..1999
  }
  for (int c = 0; c < 32; ++c) {
    __syncthreads();
    for (int idx = tid; idx < 2048; idx += 256) {
      int g = c * 2048 + idx;
      ((unsigned long long*)rows)[idx] = (g < 64000) ? mask[g] : 0ull;
    }
    __syncthreads();
    if (tid < 64) {
      for (int r = 0; r < 64; ++r) {
        int i = c * 64 + r;
        unsigned long long rw = rows[r][lane & 31];
        unsigned long long aw = __shfl(myword, i >> 6);
        if ((aw >> (i & 63)) & 1ull) {
          if (lane < 32) myword &= ~rw;
        }
      }
    }
  }
  __syncthreads();
  if (tid < 32) aliveOut[tid] = myword;
}

// ---------------- finalize: stable top-300 of kept (alive order == score order) ----------------
__global__ __launch_bounds__(1024) void finalize(const unsigned long long* __restrict__ alive,
                                                 const double4* __restrict__ boxes,
                                                 const float* __restrict__ scores,
                                                 float* __restrict__ out) {
  __shared__ int ps[1024];
  int t = threadIdx.x;
  int e0 = 2 * t, e1 = 2 * t + 1;
  int f0 = (e0 < 2000) ? (int)((alive[e0 >> 6] >> (e0 & 63)) & 1ull) : 0;
  int f1 = (e1 < 2000) ? (int)((alive[e1 >> 6] >> (e1 & 63)) & 1ull) : 0;
  int v = f0 + f1;
  ps[t] = v; __syncthreads();
  for (int off = 1; off < 1024; off <<= 1) {
    int a = ps[t];
    int b = (t >= off) ? ps[t - off] : 0;
    __syncthreads();
    ps[t] = a + b;
    __syncthreads();
  }
  int incl = ps[t];
  int excl = incl - v;
  int Na = ps[1023];
  if (f0 && excl < 300) {
    double4 bx = boxes[e0];
    out[excl * 5 + 0] = 0.f; out[excl * 5 + 1] = (float)bx.x; out[excl * 5 + 2] = (float)bx.y;
    out[excl * 5 + 3] = (float)bx.z; out[excl * 5 + 4] = (float)bx.w;
    out[1500 + excl] = scores[e0];
  }
  int p1 = excl + f0;
  if (f1 && p1 < 300) {
    double4 bx = boxes[e1];
    out[p1 * 5 + 0] = 0.f; out[p1 * 5 + 1] = (float)bx.x; out[p1 * 5 + 2] = (float)bx.y;
    out[p1 * 5 + 3] = (float)bx.z; out[p1 * 5 + 4] = (float)bx.w;
    out[1500 + p1] = scores[e1];
  }
  if (Na < 300) {
    if (e0 < 2000 && !f0) {
      int q = Na + (e0 - excl);
      if (q < 300) {
        double4 bx = boxes[e0];
        out[q * 5 + 0] = 0.f; out[q * 5 + 1] = (float)bx.x; out[q * 5 + 2] = (float)bx.y;
        out[q * 5 + 3] = (float)bx.z; out[q * 5 + 4] = (float)bx.w;
        out[1500 + q] = -__builtin_inff();
      }
    }
    if (e1 < 2000 && !f1) {
      int q = Na + (e1 - (excl + f0));
      if (q < 300) {
        double4 bx = boxes[e1];
        out[q * 5 + 0] = 0.f; out[q * 5 + 1] = (float)bx.x; out[q * 5 + 2] = (float)bx.y;
        out[q * 5 + 3] = (float)bx.z; out[q * 5 + 4] = (float)bx.w;
        out[1500 + q] = -__builtin_inff();
      }
    }
  }
}

extern "C" void kernel_launch(void* const* d_in, const int* in_sizes, int n_in,
                              void* d_out, int out_size, void* d_ws, size_t ws_size,
                              hipStream_t stream) {
  (void)in_sizes; (void)n_in; (void)out_size; (void)ws_size;
  const float* feat = (const float*)d_in[0];
  const float* w1   = (const float*)d_in[1];
  const float* b1   = (const float*)d_in[2];
  const float* sw   = (const float*)d_in[3];
  const float* sb   = (const float*)d_in[4];
  const float* bw   = (const float*)d_in[5];
  const float* bb   = (const float*)d_in[6];
  const float* info = (const float*)d_in[7];
  float* out = (float*)d_out;

  char* ws = (char*)d_ws;
  size_t off = 0;
  auto alloc = [&](size_t bytes) -> void* {
    void* p = ws + off;
    off += (bytes + 255) & ~(size_t)255;
    return p;
  };
  float* x        = (float*)alloc((size_t)512 * Mm * 4);
  float* wT       = (float*)alloc((size_t)9 * 512 * 512 * 4);
  double* w54     = (double*)alloc((size_t)54 * 512 * 8);
  float* cls      = (float*)alloc((size_t)18 * Mm * 4);
  float* dl       = (float*)alloc((size_t)36 * Mm * 4);
  double4* props  = (double4*)alloc((size_t)NP * 32);
  float* scoresF  = (float*)alloc((size_t)NP * 4);
  unsigned long long* keys64 = (unsigned long long*)alloc((size_t)NP * 8);
  unsigned* keys32 = (unsigned*)alloc((size_t)NP * 4);
  unsigned* hist   = (unsigned*)alloc((size_t)65536 * 4);
  int* Bptr        = (int*)alloc(256);
  int* cnt         = (int*)alloc(256);
  unsigned long long* cand = (unsigned long long*)alloc((size_t)8192 * 8);
  double4* boxes2000 = (double4*)alloc((size_t)2000 * 32);
  float* score2000   = (float*)alloc((size_t)2000 * 4);
  unsigned long long* mask  = (unsigned long long*)alloc((size_t)2000 * 32 * 8);
  unsigned long long* alive = (unsigned long long*)alloc((size_t)32 * 8);

  hipMemsetAsync(hist, 0, 65536 * 4, stream);
  hipMemsetAsync(cnt, 0, 4, stream);

  prep_wT<<<dim3(16, 16), 256, 0, stream>>>(w1, wT);
  prep_w54<<<108, 256, 0, stream>>>(sw, bw, w54);
  conv3x3<<<dim3(235, 4), 256, 0, stream>>>(feat, wT, b1, x);
  conv1x1<<<dim3(59, 6), 256, 0, stream>>>(x, w54, sb, bb, cls, dl);
  decode<<<528, 256, 0, stream>>>(cls, dl, info, props, scoresF, keys64, keys32, hist);
  cutoff_k<<<1, 1024, 0, stream>>>(hist, Bptr);
  compact_k<<<528, 256, 0, stream>>>(keys32, keys64, Bptr, cand, cnt);
  sort_top<<<1, 1024, 0, stream>>>(cand, cnt, props, scoresF, boxes2000, score2000);
  nms_mask<<<250, 256, 0, stream>>>(boxes2000, mask);
  suppress<<<1, 256, 0, stream>>>(mask, alive);
  finalize<<<1, 1024, 0, stream>>>(alive, boxes2000, score2000, out);
}

// Round 8
// 1835.766 us; speedup vs baseline: 1.0898x; 1.0898x over previous
//
#include <hip/hip_runtime.h>
#include <math.h>

#define Hh 100
#define Ww 150
#define Mm 15000
#define NP 135000   // 15000*9

typedef double f64x4 __attribute__((ext_vector_type(4)));

// f64 MFMA: builtin exists only in the device pass; host pass parses but never runs it.
#if defined(__HIP_DEVICE_COMPILE__)
#if __has_builtin(__builtin_amdgcn_mfma_f64_16x16x4f64)
#define MFMA64(a,b,c) __builtin_amdgcn_mfma_f64_16x16x4f64((a),(b),(c),0,0,0)
#elif __has_builtin(__builtin_amdgcn_mfma_f64_16x16x4_f64)
#define MFMA64(a,b,c) __builtin_amdgcn_mfma_f64_16x16x4_f64((a),(b),(c),0,0,0)
#else
#error "no f64 mfma builtin on device"
#endif
#else
#define MFMA64(a,b,c) (c)
#endif

__constant__ double ANCH[9][4] = {
  {-84.0,-40.0,99.0,55.0},{-176.0,-88.0,191.0,103.0},{-360.0,-184.0,375.0,191.0},
  {-56.0,-56.0,71.0,71.0},{-120.0,-120.0,135.0,135.0},{-248.0,-248.0,263.0,263.0},
  {-36.0,-80.0,51.0,95.0},{-80.0,-168.0,95.0,183.0},{-168.0,-344.0,183.0,359.0}};

// ---------------- prep: LDS-tiled transpose of conv1 weights to [tap][ci][co] ----------------
__global__ __launch_bounds__(256) void prep_wT(const float* __restrict__ w,
                                               float* __restrict__ wT) {
  __shared__ float t[32][32][10];  // [ci][co][tap], pad 9->10
  const int co0 = blockIdx.x * 32, ci0 = blockIdx.y * 32;
  for (int e = threadIdx.x; e < 9216; e += 256) {
    int cr = e / 288;
    int rem = e - cr * 288;
    int cir = rem / 9, tap = rem - cir * 9;
    t[cir][cr][tap] = w[(size_t)(co0 + cr) * 4608 + (ci0 + cir) * 9 + tap];
  }
  __syncthreads();
  for (int e = threadIdx.x; e < 9216; e += 256) {
    int tap = e / 1024;
    int rem = e - tap * 1024;
    int cir = rem >> 5, cr = rem & 31;
    wT[(size_t)tap * 262144 + (size_t)(ci0 + cir) * 512 + (co0 + cr)] = t[cir][cr][tap];
  }
}

// ---------------- prep: f64 1x1 weights ----------------
__global__ void prep_w54(const float* __restrict__ sw, const float* __restrict__ bw,
                         double* __restrict__ w54) {
  int idx = blockIdx.x * 256 + threadIdx.x;
  if (idx < 54 * 512) {
    int o = idx >> 9, c = idx & 511;
    w54[idx] = (double)((o < 18) ? sw[o * 512 + c] : bw[(o - 18) * 512 + c]);
  }
}

// ---------------- conv3x3 512->512 SAME + bias + relu via f64 MFMA ----------------
// block: 256 thr = 4 waves; tile 64px x 128co; wave tile 32px x 64co (2 M-frag x 4 N-frag).
// Single-buffer LDS, K=32 chunks. D-layout probe moved to EPILOGUE so probe results are
// not live across the main loop -> VGPR<=64, combined with 64 AGPR acc = 128 -> 4 waves/SIMD.
__global__ __launch_bounds__(256, 4) void conv3x3(const float* __restrict__ feat,
                                                  const float* __restrict__ wT,
                                                  const float* __restrict__ bias,
                                                  float* __restrict__ x) {
  __shared__ union {
    struct { float A[32][72]; float B[32][136]; } s;   // 9.2 + 17.4 KB
    float Lx[128][65];                                  // 33.3 KB epilogue transpose
  } sm;
  const int tid = threadIdx.x;
  const int lane = tid & 63;
  const int wv = tid >> 6;            // wave 0..3
  const int pw = (wv & 1) * 32;       // wave px offset
  const int cw = (wv >> 1) * 64;      // wave co offset
  const int m0 = blockIdx.x * 64;
  const int n0 = blockIdx.y * 128;
  const int l15 = lane & 15, l4 = lane >> 4;

  f64x4 zero; zero[0] = 0.0; zero[1] = 0.0; zero[2] = 0.0; zero[3] = 0.0;
  f64x4 acc[2][4];
#pragma unroll
  for (int i = 0; i < 2; ++i)
#pragma unroll
    for (int q = 0; q < 4; ++q) acc[i][q] = zero;

  // A staging: thread -> (px = tid&63, k = (tid>>6)*8 + kk)
  const int pa = tid & 63;
  const int ka = (tid >> 6) * 8;
  const int ma = m0 + pa;
  const int ha = ma / 150, wa = ma - ha * 150;
  // B staging: thread -> (co-quad = tid&31, k = (tid>>5)*4 + kk)
  const int cq = tid & 31;
  const int kb = (tid >> 5) * 4;

  for (int tap = 0; tap < 9; ++tap) {
    const int dy = tap / 3 - 1, dx = tap - (tap / 3) * 3 - 1;
    const int hh = ha + dy, wwp = wa + dx;
    const bool ok = (ma < Mm) && (hh >= 0) && (hh < Hh) && (wwp >= 0) && (wwp < Ww);
    const int src = hh * Ww + wwp;
    const float* wb = wT + (size_t)tap * 262144 + n0;
    for (int cb = 0; cb < 512; cb += 32) {
#pragma unroll
      for (int kk = 0; kk < 8; ++kk)
        sm.s.A[ka + kk][pa] = ok ? feat[(size_t)(cb + ka + kk) * Mm + src] : 0.0f;
#pragma unroll
      for (int kk = 0; kk < 4; ++kk)
        *(float4*)&sm.s.B[kb + kk][cq * 4] = *(const float4*)&wb[(size_t)(cb + kb + kk) * 512 + cq * 4];
      __syncthreads();
#pragma unroll
      for (int t = 0; t < 8; ++t) {
        const int kt = t * 4 + l4;
        const double a0 = (double)sm.s.A[kt][pw + l15];
        const double a1 = (double)sm.s.A[kt][pw + 16 + l15];
        const double b0 = (double)sm.s.B[kt][cw + l15];
        const double b1 = (double)sm.s.B[kt][cw + 16 + l15];
        const double b2 = (double)sm.s.B[kt][cw + 32 + l15];
        const double b3 = (double)sm.s.B[kt][cw + 48 + l15];
        acc[0][0] = MFMA64(a0, b0, acc[0][0]);
        acc[0][1] = MFMA64(a0, b1, acc[0][1]);
        acc[0][2] = MFMA64(a0, b2, acc[0][2]);
        acc[0][3] = MFMA64(a0, b3, acc[0][3]);
        acc[1][0] = MFMA64(a1, b0, acc[1][0]);
        acc[1][1] = MFMA64(a1, b1, acc[1][1]);
        acc[1][2] = MFMA64(a1, b2, acc[1][2]);
        acc[1][3] = MFMA64(a1, b3, acc[1][3]);
      }
      __syncthreads();
    }
  }

  // --- derive D fragment layout (probe MFMAs, epilogue-only live range) ---
  const double ap1 = (l4 == 0) ? (double)l15 : 0.0;   // A[i][k] = i * (k==0)
  const double bp1 = (l4 == 0) ? 1.0 : 0.0;           // B[k][j] = (k==0)
  const f64x4 rowp = MFMA64(ap1, bp1, zero);          // D[i][j] = i
  const double ap2 = (l4 == 0) ? 1.0 : 0.0;
  const double bp2 = (l4 == 0) ? (double)l15 : 0.0;   // B[k][j] = j * (k==0)
  const f64x4 colp = MFMA64(ap2, bp2, zero);          // D[i][j] = j

  // epilogue: bias + relu in f64, layout-probe-driven transpose via LDS, coalesced store
#pragma unroll
  for (int i = 0; i < 2; ++i)
#pragma unroll
    for (int q = 0; q < 4; ++q)
#pragma unroll
      for (int r = 0; r < 4; ++r) {
        const int row = pw + i * 16 + (int)rowp[r];   // pixel within tile
        const int col = cw + q * 16 + (int)colp[r];   // out-channel within tile
        const double v = acc[i][q][r] + (double)bias[n0 + col];
        sm.Lx[col][row] = (float)(v > 0.0 ? v : 0.0);
      }
  __syncthreads();
  for (int e = tid; e < 64 * 128; e += 256) {
    const int co = e >> 6, p = e & 63;
    const int m = m0 + p;
    if (m < Mm) x[(size_t)(n0 + co) * Mm + m] = sm.Lx[co][p];
  }
}

// ---------------- fused 1x1 convs: 18 cls + 36 deltas, f64 accumulate, split over 6 groups ----------------
__global__ __launch_bounds__(256) void conv1x1(const float* __restrict__ x,
                                               const double* __restrict__ w54,
                                               const float* __restrict__ sb,
                                               const float* __restrict__ bb,
                                               float* __restrict__ cls,
                                               float* __restrict__ dl) {
  int m = blockIdx.x * 256 + threadIdx.x;
  int g = blockIdx.y;  // 0..5, each handles 9 outputs
  double acc[9];
#pragma unroll
  for (int o = 0; o < 9; ++o) acc[o] = 0.0;
  if (m < Mm) {
    const double* wg = w54 + (size_t)g * 9 * 512;
    for (int c = 0; c < 512; ++c) {
      double v = (double)x[(size_t)c * Mm + m];
#pragma unroll
      for (int o = 0; o < 9; ++o) acc[o] += v * wg[o * 512 + c];
    }
#pragma unroll
    for (int o = 0; o < 9; ++o) {
      int oo = g * 9 + o;
      if (oo < 18) cls[oo * Mm + m] = (float)(acc[o] + (double)sb[oo]);
      else dl[(oo - 18) * Mm + m] = (float)(acc[o] + (double)bb[oo - 18]);
    }
  }
}

// ---------------- softmax + box decode + filter + sortable keys (+ fused histogram) ----------------
__global__ void decode(const float* __restrict__ cls, const float* __restrict__ dl,
                       const float* __restrict__ info, double4* __restrict__ props,
                       float* __restrict__ scoresF, unsigned long long* __restrict__ keys64,
                       unsigned* __restrict__ keys32, unsigned* __restrict__ hist) {
  int i = blockIdx.x * 256 + threadIdx.x;
  if (i >= NP) return;
  int m = i / 9, a = i - m * 9;
  int h = m / 150, w = m - h * 150;
  double c0 = (double)cls[a * Mm + m], c1 = (double)cls[(9 + a) * Mm + m];
  double mx = fmax(c0, c1);
  double e0 = exp(c0 - mx), e1 = exp(c1 - mx);
  double p = e1 / (e0 + e1);
  double d0 = (double)dl[(a * 4 + 0) * Mm + m], d1 = (double)dl[(a * 4 + 1) * Mm + m];
  double d2 = (double)dl[(a * 4 + 2) * Mm + m], d3 = (double)dl[(a * 4 + 3) * Mm + m];
  double sx = (double)w * 16.0, sy = (double)h * 16.0;
  double ax1 = ANCH[a][0] + sx, ay1 = ANCH[a][1] + sy;
  double ax2 = ANCH[a][2] + sx, ay2 = ANCH[a][3] + sy;
  double aw = ax2 - ax1 + 1.0, ah = ay2 - ay1 + 1.0;
  double cx = ax1 + 0.5 * aw, cy = ay1 + 0.5 * ah;
  double pcx = d0 * aw + cx, pcy = d1 * ah + cy;
  double pw = exp(d2) * aw, ph = exp(d3) * ah;
  double x1 = pcx - 0.5 * pw, y1 = pcy - 0.5 * ph;
  double x2 = pcx + 0.5 * pw, y2 = pcy + 0.5 * ph;
  double IH = (double)info[0], IW = (double)info[1], sc = (double)info[2];
  x1 = fmin(fmax(x1, 0.0), IW - 1.0); y1 = fmin(fmax(y1, 0.0), IH - 1.0);
  x2 = fmin(fmax(x2, 0.0), IW - 1.0); y2 = fmin(fmax(y2, 0.0), IH - 1.0);
  double bwd = x2 - x1 + 1.0, bhd = y2 - y1 + 1.0;
  bool valid = (bwd >= 16.0 * sc) && (bhd >= 16.0 * sc);
  double score = valid ? p : -__builtin_inf();
  double4 pr; pr.x = x1; pr.y = y1; pr.z = x2; pr.w = y2;
  props[i] = pr;
  float pf = (float)score;
  scoresF[i] = pf;
  unsigned long long b = (unsigned long long)__double_as_longlong(score);
  unsigned long long s = (b >> 63) ? ~b : (b | 0x8000000000000000ull);
  unsigned long long k = ~s;                      // ascending key == descending score
  keys64[i] = (k & ~0x3FFFFull) | (unsigned long long)i;  // idx tiebreak (stable top_k)
  unsigned ub = __float_as_uint(pf);
  unsigned us = (ub >> 31) ? ~ub : (ub | 0x80000000u);
  unsigned k32 = ~us;
  keys32[i] = k32;
  atomicAdd(&hist[k32 >> 16], 1u);
}

// ---------------- find cutoff bin B: cum(<=B) >= 2000, cum(<B) < 2000 ----------------
__global__ __launch_bounds__(1024) void cutoff_k(const unsigned* __restrict__ hist,
                                                 int* __restrict__ Bout) {
  __shared__ unsigned ps[1024];
  int t = threadIdx.x;
  unsigned s = 0;
  for (int b = t * 64; b < t * 64 + 64; ++b) s += hist[b];
  ps[t] = s; __syncthreads();
  for (int off = 1; off < 1024; off <<= 1) {
    unsigned a = ps[t];
    unsigned bb2 = (t >= off) ? ps[t - off] : 0u;
    __syncthreads();
    ps[t] = a + bb2;
    __syncthreads();
  }
  unsigned excl = ps[t] - s;
  if (excl < 2000u) {
    unsigned run = excl;
    for (int b = t * 64; b < t * 64 + 64; ++b) {
      unsigned nb = run + hist[b];
      if (run < 2000u && nb >= 2000u) *Bout = b;
      run = nb;
    }
  }
}

// ---------------- compact candidates (bin <= B) ----------------
__global__ void compact_k(const unsigned* __restrict__ keys32,
                          const unsigned long long* __restrict__ keys64,
                          const int* __restrict__ Bptr,
                          unsigned long long* __restrict__ cand, int* __restrict__ cnt) {
  int i = blockIdx.x * 256 + threadIdx.x;
  if (i >= NP) return;
  int B = *Bptr;
  if ((int)(keys32[i] >> 16) <= B) {
    int pos = atomicAdd(cnt, 1);
    if (pos < 8192) cand[pos] = keys64[i];
  }
}

// ---------------- single-block bitonic sort of 8192 candidate keys; emit top-2000 ----------------
__global__ __launch_bounds__(1024) void sort_top(const unsigned long long* __restrict__ cand,
                                                 const int* __restrict__ pcnt,
                                                 const double4* __restrict__ props,
                                                 const float* __restrict__ scoresF,
                                                 double4* __restrict__ boxes2000,
                                                 float* __restrict__ score2000) {
  __shared__ unsigned long long sh[8192];  // 64 KB
  int t = threadIdx.x;
  int cnt = *pcnt; if (cnt > 8192) cnt = 8192;
  for (int i = t; i < 8192; i += 1024) sh[i] = (i < cnt) ? cand[i] : ~0ull;
  __syncthreads();
  for (int kb = 1; kb <= 13; ++kb) {
    int k = 1 << kb;
    for (int jb = kb - 1; jb >= 0; --jb) {
      int j = 1 << jb;
      for (int s = t; s < 4096; s += 1024) {
        int i = ((s >> jb) << (jb + 1)) | (s & (j - 1));
        int l = i + j;
        bool up = ((i & k) == 0);
        unsigned long long a = sh[i], b = sh[l];
        if (up ? (a > b) : (a < b)) { sh[i] = b; sh[l] = a; }
      }
      __syncthreads();
    }
  }
  for (int r = t; r < 2000; r += 1024) {
    unsigned long long key = sh[r];
    int idx = (int)(key & 0x3FFFFull);
    boxes2000[r] = props[idx];
    score2000[r] = scoresF[idx];
  }
}

// ---------------- NMS pairwise IoU bitmask (f64) ----------------
__global__ __launch_bounds__(256) void nms_mask(const double4* __restrict__ boxes,
                                                unsigned long long* __restrict__ mask) {
  int tid = threadIdx.x;
  int r = blockIdx.x * 8 + (tid >> 5);
  int wd = tid & 31;
  double4 bi = boxes[r];
  double ai = (bi.z - bi.x + 1.0) * (bi.w - bi.y + 1.0);
  unsigned long long bits = 0;
  int j0 = wd * 64;
  int jmax = 2000 - j0; if (jmax > 64) jmax = 64;
  for (int jj = 0; jj < jmax; ++jj) {
    int j = j0 + jj;
    if (j > r) {
      double4 bj = boxes[j];
      double xx1 = fmax(bi.x, bj.x), yy1 = fmax(bi.y, bj.y);
      double xx2 = fmin(bi.z, bj.z), yy2 = fmin(bi.w, bj.w);
      double w_ = fmax(xx2 - xx1 + 1.0, 0.0), h_ = fmax(yy2 - yy1 + 1.0, 0.0);
      double inter = w_ * h_;
      double aj = (bj.z - bj.x + 1.0) * (bj.w - bj.y + 1.0);
      double iou = inter / (ai + aj - inter);
      if (iou > 0.7) bits |= 1ull << jj;
    }
  }
  mask[r * 32 + wd] = bits;
}

// ---------------- sequential greedy suppress (single wave, shfl alive-bitmask) ----------------
__global__ __launch_bounds__(256) void suppress(const unsigned long long* __restrict__ mask,
                                                unsigned long long* __restrict__ aliveOut) {
  __shared__ unsigned long long rows[64][32];  // 16 KB chunk of mask rows
  int tid = threadIdx.x;
  int lane = tid & 63;
  unsigned long long myword = 0;
  if (tid < 64) {
    if (lane < 31) myword = ~0ull;
    else if (lane == 31) myword = 0xFFFFull;  // bits 1984..1999
  }
  for (int c = 0; c < 32; ++c) {
    __syncthreads();
    for (int idx = tid; idx < 2048; idx += 256) {
      int g = c * 2048 + idx;
      ((unsigned long long*)rows)[idx] = (g < 64000) ? mask[g] : 0ull;
    }
    __syncthreads();
    if (tid < 64) {
      for (int r = 0; r < 64; ++r) {
        int i = c * 64 + r;
        unsigned long long rw = rows[r][lane & 31];
        unsigned long long aw = __shfl(myword, i >> 6);
        if ((aw >> (i & 63)) & 1ull) {
          if (lane < 32) myword &= ~rw;
        }
      }
    }
  }
  __syncthreads();
  if (tid < 32) aliveOut[tid] = myword;
}

// ---------------- finalize: stable top-300 of kept (alive order == score order) ----------------
__global__ __launch_bounds__(1024) void finalize(const unsigned long long* __restrict__ alive,
                                                 const double4* __restrict__ boxes,
                                                 const float* __restrict__ scores,
                                                 float* __restrict__ out) {
  __shared__ int ps[1024];
  int t = threadIdx.x;
  int e0 = 2 * t, e1 = 2 * t + 1;
  int f0 = (e0 < 2000) ? (int)((alive[e0 >> 6] >> (e0 & 63)) & 1ull) : 0;
  int f1 = (e1 < 2000) ? (int)((alive[e1 >> 6] >> (e1 & 63)) & 1ull) : 0;
  int v = f0 + f1;
  ps[t] = v; __syncthreads();
  for (int off = 1; off < 1024; off <<= 1) {
    int a = ps[t];
    int b = (t >= off) ? ps[t - off] : 0;
    __syncthreads();
    ps[t] = a + b;
    __syncthreads();
  }
  int incl = ps[t];
  int excl = incl - v;
  int Na = ps[1023];
  if (f0 && excl < 300) {
    double4 bx = boxes[e0];
    out[excl * 5 + 0] = 0.f; out[excl * 5 + 1] = (float)bx.x; out[excl * 5 + 2] = (float)bx.y;
    out[excl * 5 + 3] = (float)bx.z; out[excl * 5 + 4] = (float)bx.w;
    out[1500 + excl] = scores[e0];
  }
  int p1 = excl + f0;
  if (f1 && p1 < 300) {
    double4 bx = boxes[e1];
    out[p1 * 5 + 0] = 0.f; out[p1 * 5 + 1] = (float)bx.x; out[p1 * 5 + 2] = (float)bx.y;
    out[p1 * 5 + 3] = (float)bx.z; out[p1 * 5 + 4] = (float)bx.w;
    out[1500 + p1] = scores[e1];
  }
  if (Na < 300) {
    if (e0 < 2000 && !f0) {
      int q = Na + (e0 - excl);
      if (q < 300) {
        double4 bx = boxes[e0];
        out[q * 5 + 0] = 0.f; out[q * 5 + 1] = (float)bx.x; out[q * 5 + 2] = (float)bx.y;
        out[q * 5 + 3] = (float)bx.z; out[q * 5 + 4] = (float)bx.w;
        out[1500 + q] = -__builtin_inff();
      }
    }
    if (e1 < 2000 && !f1) {
      int q = Na + (e1 - (excl + f0));
      if (q < 300) {
        double4 bx = boxes[e1];
        out[q * 5 + 0] = 0.f; out[q * 5 + 1] = (float)bx.x; out[q * 5 + 2] = (float)bx.y;
        out[q * 5 + 3] = (float)bx.z; out[q * 5 + 4] = (float)bx.w;
        out[1500 + q] = -__builtin_inff();
      }
    }
  }
}

extern "C" void kernel_launch(void* const* d_in, const int* in_sizes, int n_in,
                              void* d_out, int out_size, void* d_ws, size_t ws_size,
                              hipStream_t stream) {
  (void)in_sizes; (void)n_in; (void)out_size; (void)ws_size;
  const float* feat = (const float*)d_in[0];
  const float* w1   = (const float*)d_in[1];
  const float* b1   = (const float*)d_in[2];
  const float* sw   = (const float*)d_in[3];
  const float* sb   = (const float*)d_in[4];
  const float* bw   = (const float*)d_in[5];
  const float* bb   = (const float*)d_in[6];
  const float* info = (const float*)d_in[7];
  float* out = (float*)d_out;

  char* ws = (char*)d_ws;
  size_t off = 0;
  auto alloc = [&](size_t bytes) -> void* {
    void* p = ws + off;
    off += (bytes + 255) & ~(size_t)255;
    return p;
  };
  float* x        = (float*)alloc((size_t)512 * Mm * 4);
  float* wT       = (float*)alloc((size_t)9 * 512 * 512 * 4);
  double* w54     = (double*)alloc((size_t)54 * 512 * 8);
  float* cls      = (float*)alloc((size_t)18 * Mm * 4);
  float* dl       = (float*)alloc((size_t)36 * Mm * 4);
  double4* props  = (double4*)alloc((size_t)NP * 32);
  float* scoresF  = (float*)alloc((size_t)NP * 4);
  unsigned long long* keys64 = (unsigned long long*)alloc((size_t)NP * 8);
  unsigned* keys32 = (unsigned*)alloc((size_t)NP * 4);
  unsigned* hist   = (unsigned*)alloc((size_t)65536 * 4);
  int* Bptr        = (int*)alloc(256);
  int* cnt         = (int*)alloc(256);
  unsigned long long* cand = (unsigned long long*)alloc((size_t)8192 * 8);
  double4* boxes2000 = (double4*)alloc((size_t)2000 * 32);
  float* score2000   = (float*)alloc((size_t)2000 * 4);
  unsigned long long* mask  = (unsigned long long*)alloc((size_t)2000 * 32 * 8);
  unsigned long long* alive = (unsigned long long*)alloc((size_t)32 * 8);

  hipMemsetAsync(hist, 0, 65536 * 4, stream);
  hipMemsetAsync(cnt, 0, 4, stream);

  prep_wT<<<dim3(16, 16), 256, 0, stream>>>(w1, wT);
  prep_w54<<<108, 256, 0, stream>>>(sw, bw, w54);
  conv3x3<<<dim3(235, 4), 256, 0, stream>>>(feat, wT, b1, x);
  conv1x1<<<dim3(59, 6), 256, 0, stream>>>(x, w54, sb, bb, cls, dl);
  decode<<<528, 256, 0, stream>>>(cls, dl, info, props, scoresF, keys64, keys32, hist);
  cutoff_k<<<1, 1024, 0, stream>>>(hist, Bptr);
  compact_k<<<528, 256, 0, stream>>>(keys32, keys64, Bptr, cand, cnt);
  sort_top<<<1, 1024, 0, stream>>>(cand, cnt, props, scoresF, boxes2000, score2000);
  nms_mask<<<250, 256, 0, stream>>>(boxes2000, mask);
  suppress<<<1, 256, 0, stream>>>(mask, alive);
  finalize<<<1, 1024, 0, stream>>>(alive, boxes2000, score2000, out);
}